// Round 1
// baseline (242.369 us; speedup 1.0000x reference)
//
#include <hip/hip_runtime.h>
#include <hip/hip_bf16.h>
#include <math.h>

// Round 12: occupancy attack. fusion_attn was latency-bound (MfmaUtil 12%,
// VALUBusy 18%, HBM 13%, Occupancy 28%) with LDS (53.7KB -> 3 blocks/CU)
// as the occupancy cap. Change: TP 32->16 pixels per block.
//   - LDS 26.9KB -> 6 blocks/CU (24 waves, 75% ceiling vs 37.5%)
//   - mf loop collapses (2->1): halved fragments, __launch_bounds__(256,6)
//   - Phase-A LDS stores go 4-way -> 2-way bank aliasing (free)
//   - bijective XCD swizzle (4096%8==0) keeps adjacent 16-pix tiles on one
//     XCD's L2 (64B = half-line reads are split with the neighbor tile)
// Arithmetic order per pixel identical to R11 -> absmax unchanged.
// B=4 N=6 C=128 H=W=128, HEADS=4 HD=32 MID=32.

#define BB   4
#define NV   6
#define CH   128
#define HGT  128
#define WID  128
#define MIDD 32
#define HWP  (HGT*WID)
#define TP   16

#define SWZ(pix) (((pix) & 15) << 3)

typedef __attribute__((ext_vector_type(8))) short bf16x8;
typedef __attribute__((ext_vector_type(4))) float f32x4;
typedef __attribute__((ext_vector_type(2))) unsigned int uint2v;

union U8 { bf16x8 v; unsigned u[4]; };

__device__ __forceinline__ ushort f2bf(float f) {
    union { __hip_bfloat16 h; ushort u; } v;
    v.h = __float2bfloat16(f);
    return v.u;
}
__device__ __forceinline__ float bf2f(ushort u) {
    return __uint_as_float(((unsigned)u) << 16);
}
__device__ __forceinline__ unsigned cvt_pk_bf16(float lo, float hi) {
    unsigned r;
    asm("v_cvt_pk_bf16_f32 %0, %1, %2" : "=v"(r) : "v"(lo), "v"(hi));
    return r;
}

// ---------------- setup: rel_bias, gate ----------------
__global__ void fusion_setup(const float* __restrict__ snr, const float* __restrict__ vr,
                             const float* __restrict__ Wg, const float* __restrict__ bg,
                             const float* __restrict__ Wr1, const float* __restrict__ br1,
                             const float* __restrict__ Wr2, const float* __restrict__ br2,
                             float* __restrict__ relb, float* __restrict__ gate)
{
    int tid = blockIdx.x * blockDim.x + threadIdx.x;
    if (tid < BB*CH) {
        int b = tid >> 7, c = tid & 127;
        float s = snr[b] * 0.05f;
        s = fminf(fmaxf(s, -1.5f), 1.5f);
        float z = s * Wg[c] + bg[c];
        gate[tid] = 1.0f / (1.0f + __expf(-z));
    }
    if (tid < BB*NV) {
        int b = tid / NV, n = tid % NV;
        float v0 = vr[(b*NV+n)*3+0], v1 = vr[(b*NV+n)*3+1], v2 = vr[(b*NV+n)*3+2];
        float acc = br2[0];
        for (int j = 0; j < MIDD; ++j) {
            float h = Wr1[j*3+0]*v0 + Wr1[j*3+1]*v1 + Wr1[j*3+2]*v2 + br1[j];
            acc += Wr2[j] * fmaxf(h, 0.0f);
        }
        relb[tid] = acc;
    }
}

// ---------------- weight frag-packing ----------------
__global__ void pack_weights(const float* __restrict__ Wq, const float* __restrict__ Wk,
                             const float* __restrict__ Wv, const float* __restrict__ Wo1,
                             const float* __restrict__ Wc1, const float* __restrict__ Wo2,
                             ushort* __restrict__ wqp, ushort* __restrict__ wkp,
                             ushort* __restrict__ wvp, ushort* __restrict__ wo1p,
                             ushort* __restrict__ wc1p, ushort* __restrict__ wo2p)
{
    int tid = blockIdx.x * 256 + threadIdx.x;
    if (tid >= 27136) return;
    if (tid < 8192) {
        int m = tid >> 11;
        int local = tid & 2047;
        const float* src = (m == 0) ? Wq : (m == 1) ? Wk : (m == 2) ? Wv : Wo1;
        ushort* dst = (m == 0) ? wqp : (m == 1) ? wkp : (m == 2) ? wvp : wo1p;
        int ks = local >> 9, rem = local & 511;
        int nf = rem >> 6, lane = rem & 63;
        int o = nf*16 + (lane & 15);
        int i0 = ks*32 + ((lane >> 4) << 3);
        const float* s = src + o*CH + i0;
        ushort* d = dst + local*8;
#pragma unroll
        for (int j = 0; j < 8; ++j) d[j] = f2bf(s[j]);
    } else if (tid < 8704) {
        int local = tid - 8192;
        int ks = local >> 7, rem = local & 127;
        int nf = rem >> 6, lane = rem & 63;
        int o = nf*16 + (lane & 15);
        int i0 = ks*32 + ((lane >> 4) << 3);
        const float* s = Wc1 + o*CH + i0;
        ushort* d = wc1p + local*8;
#pragma unroll
        for (int j = 0; j < 8; ++j) d[j] = f2bf(s[j]);
    } else {
        int l2 = tid - 8704;
        int lane = l2 & 63;
        int rest = l2 >> 6;
        int nf = rest & 7;
        int kst = rest >> 3;
        int ks = kst & 3;
        int tap = kst >> 2;
        int co = nf*16 + (lane & 15);
        int ci0 = ks*32 + ((lane >> 4) << 3);
        ushort* d = wo2p + l2*8;
#pragma unroll
        for (int j = 0; j < 8; ++j) d[j] = f2bf(Wo2[(co*CH + ci0 + j)*9 + tap]);
    }
}

// ---------------- MFMA helpers ----------------
__device__ __forceinline__ bf16x8 ldsA(const ushort* tile, int lane, int ks) {
    int pix = lane & 15;
    int idx = (pix*128 + ks*32 + ((lane >> 4) << 3)) ^ SWZ(pix);
    return *(const bf16x8*)(tile + idx);
}
__device__ __forceinline__ bf16x8 ldB(const ushort* pack, int lane, int ks, int nf, int NF) {
    return *(const bf16x8*)(pack + (((ks*NF + nf)*64) + lane)*8);
}

// ---------------- fusion_attn: per (b, 16-pix tile) ----------------
__global__ __launch_bounds__(256, 6) void fusion_attn(
    const float* __restrict__ bev,
    const ushort* __restrict__ wqp, const ushort* __restrict__ wkp,
    const ushort* __restrict__ wvp, const ushort* __restrict__ wo1p,
    const ushort* __restrict__ wc1p,
    const float* __restrict__ bq, const float* __restrict__ bk,
    const float* __restrict__ bv, const float* __restrict__ bo1,
    const float* __restrict__ bc1, const float* __restrict__ bc2,
    const float* __restrict__ Wc2, const float* __restrict__ relb,
    ushort* __restrict__ gq_bf, ushort* __restrict__ t_bf, ushort* __restrict__ fc_bf,
    float* __restrict__ attn_o, float* __restrict__ conf_o)
{
    __shared__ ushort xt[NV][TP*128];   // swizzled [pix][c] bf16; xt[0] reused for fused
    __shared__ float  scat[NV][4][TP];
    __shared__ float  lpart[NV][TP];
    __shared__ float  cfw[NV][TP];

    const int t = threadIdx.x, lane = t & 63, w = t >> 6;
    // bijective XCD swizzle: 4096 blocks, 8 XCDs -> each XCD gets 512
    // consecutive virtual tiles (adjacent pix tiles share L2 lines).
    const int vb = ((blockIdx.x & 7) << 9) | (blockIdx.x >> 3);
    const int b = vb >> 10;
    const int pix0 = (vb & 1023) * TP;

    // ---- Phase A: stage 6 views -> LDS bf16 swizzled; 3-view-deep load pipeline ----
    const int pixg = (t & 3) * 4;
    const int c0   = (t >> 2) * 2;
    const float* sb = bev + (((size_t)b*NV*CH + c0)*HWP + pix0 + pixg);
    const size_t vstep = (size_t)CH*HWP;
    float gacc[8];
#pragma unroll
    for (int i = 0; i < 8; ++i) gacc[i] = 0.f;
    float4 L[3][2];                      // rotating 3-view buffer (fully-unrolled static idx)
#pragma unroll
    for (int j = 0; j < 3; ++j) {
        const float* s1 = sb + (size_t)j*vstep;
        L[j][0] = *(const float4*)(s1);
        L[j][1] = *(const float4*)(s1 + HWP);
    }
#pragma unroll
    for (int n = 0; n < NV; ++n) {
        const int slot = n % 3;          // static under full unroll
        float4 a0 = L[slot][0], b0 = L[slot][1];
        if (n + 3 < NV) {
            const float* s1 = sb + (size_t)(n+3)*vstep;
            L[slot][0] = *(const float4*)(s1);
            L[slot][1] = *(const float4*)(s1 + HWP);
        }
        float r0[4] = {a0.x,a0.y,a0.z,a0.w};
        float r1[4] = {b0.x,b0.y,b0.z,b0.w};
#pragma unroll
        for (int p = 0; p < 4; ++p) {
            int pix = pixg + p;
            unsigned pk = cvt_pk_bf16(r0[p], r1[p]);
            *(unsigned*)(&xt[n][(pix*128 + c0) ^ SWZ(pix)]) = pk;
            gacc[p]   += r0[p];
            gacc[4+p] += r1[p];
        }
    }
    {
        uint2v g0, g1;
        g0[0] = cvt_pk_bf16(gacc[0] * (1.0f/6.0f), gacc[1] * (1.0f/6.0f));
        g0[1] = cvt_pk_bf16(gacc[2] * (1.0f/6.0f), gacc[3] * (1.0f/6.0f));
        g1[0] = cvt_pk_bf16(gacc[4] * (1.0f/6.0f), gacc[5] * (1.0f/6.0f));
        g1[1] = cvt_pk_bf16(gacc[6] * (1.0f/6.0f), gacc[7] * (1.0f/6.0f));
        ushort* gd = gq_bf + ((size_t)(b*CH + c0)*HWP + pix0 + pixg);
        *(uint2v*)(gd)       = g0;
        *(uint2v*)(gd + HWP) = g1;
    }
    __syncthreads();

    const int cl0 = (lane & 15);
    const int rg  = (lane >> 4) << 2;
    const float bqv0 = bq[w*32 + cl0],      bqv1 = bq[w*32 + 16 + cl0];
    const float bkv0 = bk[w*32 + cl0],      bkv1 = bk[w*32 + 16 + cl0];
    const float bvv0 = bv[w*32 + cl0],      bvv1 = bv[w*32 + 16 + cl0];
    const float bov0 = bo1[w*32 + cl0],     bov1 = bo1[w*32 + 16 + cl0];
    const float bc10 = bc1[cl0],            bc11 = bc1[16 + cl0];
    const float wc20 = Wc2[cl0],            wc21 = Wc2[16 + cl0];

    // ---- Pass 1: Q accumulated across views via MFMA; conf for assigned views ----
    f32x4 qf[2];
    qf[0] = (f32x4){0.f,0.f,0.f,0.f};
    qf[1] = (f32x4){0.f,0.f,0.f,0.f};
#pragma unroll 2
    for (int n = 0; n < NV; ++n) {
        bf16x8 xA[4];
#pragma unroll
        for (int ks = 0; ks < 4; ++ks) xA[ks] = ldsA(xt[n], lane, ks);
#pragma unroll
        for (int nfl = 0; nfl < 2; ++nfl) {
            int nf = 2*w + nfl;
#pragma unroll
            for (int ks = 0; ks < 4; ++ks) {
                bf16x8 bb = ldB(wqp, lane, ks, nf, 8);
                qf[nfl] = __builtin_amdgcn_mfma_f32_16x16x32_bf16(xA[ks], bb, qf[nfl], 0, 0, 0);
            }
        }
        if (n == w || n == w + 4) {
            f32x4 cf[2];
            cf[0] = (f32x4){0.f,0.f,0.f,0.f};
            cf[1] = (f32x4){0.f,0.f,0.f,0.f};
#pragma unroll
            for (int nfc = 0; nfc < 2; ++nfc) {
#pragma unroll
                for (int ks = 0; ks < 4; ++ks) {
                    bf16x8 bb = ldB(wc1p, lane, ks, nfc, 2);
                    cf[nfc] = __builtin_amdgcn_mfma_f32_16x16x32_bf16(xA[ks], bb, cf[nfc], 0, 0, 0);
                }
            }
#pragma unroll
            for (int r = 0; r < 4; ++r) {
                float pl = fmaxf(cf[0][r] + bc10, 0.f)*wc20
                         + fmaxf(cf[1][r] + bc11, 0.f)*wc21;
                pl += __shfl_xor(pl, 1, 64);
                pl += __shfl_xor(pl, 2, 64);
                pl += __shfl_xor(pl, 4, 64);
                pl += __shfl_xor(pl, 8, 64);
                if (cl0 == 0) lpart[n][rg + r] = pl;
            }
        }
    }
#pragma unroll
    for (int r = 0; r < 4; ++r) {
        qf[0][r] = qf[0][r]*(1.0f/6.0f) + bqv0;
        qf[1][r] = qf[1][r]*(1.0f/6.0f) + bqv1;
    }

    // ---- Pass 2: K per view -> scores ----
#pragma unroll 2
    for (int n = 0; n < NV; ++n) {
        bf16x8 xA[4];
#pragma unroll
        for (int ks = 0; ks < 4; ++ks) xA[ks] = ldsA(xt[n], lane, ks);
        f32x4 kf[2];
        kf[0] = (f32x4){0.f,0.f,0.f,0.f};
        kf[1] = (f32x4){0.f,0.f,0.f,0.f};
#pragma unroll
        for (int nfl = 0; nfl < 2; ++nfl) {
            int nf = 2*w + nfl;
#pragma unroll
            for (int ks = 0; ks < 4; ++ks) {
                bf16x8 bb = ldB(wkp, lane, ks, nf, 8);
                kf[nfl] = __builtin_amdgcn_mfma_f32_16x16x32_bf16(xA[ks], bb, kf[nfl], 0, 0, 0);
            }
        }
#pragma unroll
        for (int r = 0; r < 4; ++r) {
            float s = qf[0][r]*(kf[0][r] + bkv0) + qf[1][r]*(kf[1][r] + bkv1);
            s += __shfl_xor(s, 1, 64);
            s += __shfl_xor(s, 2, 64);
            s += __shfl_xor(s, 4, 64);
            s += __shfl_xor(s, 8, 64);
            if (cl0 == 0) scat[n][w][rg + r] = s * 0.17677669529663687f;
        }
    }
    __syncthreads();

    // ---- Phase D: attn softmax (t<64) || conf softmax (64<=t<80) ----
    if (t < 64) {
        int h = t >> 4, pix = t & 15;
        float s0 = scat[0][h][pix], s1 = scat[1][h][pix], s2 = scat[2][h][pix],
              s3 = scat[3][h][pix], s4 = scat[4][h][pix], s5 = scat[5][h][pix];
        float mx = fmaxf(fmaxf(fmaxf(s0,s1),fmaxf(s2,s3)),fmaxf(s4,s5));
        float e0=__expf(s0-mx), e1=__expf(s1-mx), e2=__expf(s2-mx),
              e3=__expf(s3-mx), e4=__expf(s4-mx), e5=__expf(s5-mx);
        float inv = 1.0f/(e0+e1+e2+e3+e4+e5);
        scat[0][h][pix]=e0*inv; scat[1][h][pix]=e1*inv; scat[2][h][pix]=e2*inv;
        scat[3][h][pix]=e3*inv; scat[4][h][pix]=e4*inv; scat[5][h][pix]=e5*inv;
    } else if (t < 80) {
        int pix = t - 64;
        float bc2v = bc2[0];
        float lg[NV];
#pragma unroll
        for (int n = 0; n < NV; ++n)
            lg[n] = lpart[n][pix] + bc2v + relb[b*NV + n];
        float mx = fmaxf(fmaxf(fmaxf(lg[0],lg[1]),fmaxf(lg[2],lg[3])),fmaxf(lg[4],lg[5]));
        float e[NV], sum = 0.f;
#pragma unroll
        for (int n = 0; n < NV; ++n) { e[n] = __expf(lg[n]-mx); sum += e[n]; }
        float inv = 1.0f/sum;
#pragma unroll
        for (int n = 0; n < NV; ++n) {
            float wv = e[n]*inv;
            cfw[n][pix] = wv;
            conf_o[(b*NV + n)*HWP + pix0 + pix] = wv;
        }
    }
    __syncthreads();

    // ---- Pass 3: V per view via MFMA, attn-scale C-regs ----
    f32x4 ff[2];
    ff[0] = (f32x4){0.f,0.f,0.f,0.f};
    ff[1] = (f32x4){0.f,0.f,0.f,0.f};
#pragma unroll 2
    for (int n = 0; n < NV; ++n) {
        bf16x8 xA[4];
#pragma unroll
        for (int ks = 0; ks < 4; ++ks) xA[ks] = ldsA(xt[n], lane, ks);
        f32x4 vv[2];
        vv[0] = (f32x4){0.f,0.f,0.f,0.f};
        vv[1] = (f32x4){0.f,0.f,0.f,0.f};
#pragma unroll
        for (int nfl = 0; nfl < 2; ++nfl) {
            int nf = 2*w + nfl;
#pragma unroll
            for (int ks = 0; ks < 4; ++ks) {
                bf16x8 bb = ldB(wvp, lane, ks, nf, 8);
                vv[nfl] = __builtin_amdgcn_mfma_f32_16x16x32_bf16(xA[ks], bb, vv[nfl], 0, 0, 0);
            }
        }
#pragma unroll
        for (int r = 0; r < 4; ++r) {
            float a = scat[n][w][rg + r];
            ff[0][r] += a * vv[0][r];
            ff[1][r] += a * vv[1][r];
        }
    }
#pragma unroll
    for (int r = 0; r < 4; ++r) { ff[0][r] += bvv0; ff[1][r] += bvv1; }

    // ---- fc = sum_n cfw[n]*x_n -> fc_bf NCHW bf16 ----
    {
        float fcv[8];
#pragma unroll
        for (int i = 0; i < 8; ++i) fcv[i] = 0.f;
#pragma unroll
        for (int n = 0; n < NV; ++n) {
#pragma unroll
            for (int p = 0; p < 4; ++p) {
                int pix = pixg + p;
                float cwv = cfw[n][pix];
                unsigned pk = *(const unsigned*)(&xt[n][(pix*128 + c0) ^ SWZ(pix)]);
                fcv[p]   += cwv * bf2f((ushort)(pk & 0xffffu));
                fcv[4+p] += cwv * bf2f((ushort)(pk >> 16));
            }
        }
        uint2v f0, f1;
        f0[0] = cvt_pk_bf16(fcv[0], fcv[1]);
        f0[1] = cvt_pk_bf16(fcv[2], fcv[3]);
        f1[0] = cvt_pk_bf16(fcv[4], fcv[5]);
        f1[1] = cvt_pk_bf16(fcv[6], fcv[7]);
        ushort* fd = fc_bf + ((size_t)(b*CH + c0)*HWP + pix0 + pixg);
        *(uint2v*)(fd)       = f0;
        *(uint2v*)(fd + HWP) = f1;
    }
    if (t < 96) {
        int n = t >> 4, pix = t & 15;
        float am = 0.25f*(scat[n][0][pix]+scat[n][1][pix]+scat[n][2][pix]+scat[n][3][pix]);
        attn_o[(b*NV + n)*HWP + pix0 + pix] = am;
    }
    __syncthreads();

    // ---- fused frags -> xt[0] (swizzled) ----
    {
        ushort* xt0 = &xt[0][0];
#pragma unroll
        for (int nfl = 0; nfl < 2; ++nfl)
#pragma unroll
            for (int r = 0; r < 4; ++r) {
                int pix = rg + r;
                int c   = w*32 + nfl*16 + cl0;
                xt0[(pix*128 + c) ^ SWZ(pix)] = f2bf(ff[nfl][r]);
            }
    }
    __syncthreads();

    // ---- Phase F: t = relu(Wo1 @ fused + bo1) -> t_bf NHWC bf16 ----
    {
        bf16x8 aA[4];
#pragma unroll
        for (int ks = 0; ks < 4; ++ks) aA[ks] = ldsA(&xt[0][0], lane, ks);
        f32x4 tf[2];
        tf[0] = (f32x4){0.f,0.f,0.f,0.f};
        tf[1] = (f32x4){0.f,0.f,0.f,0.f};
#pragma unroll
        for (int nfl = 0; nfl < 2; ++nfl) {
            int nf = 2*w + nfl;
#pragma unroll
            for (int ks = 0; ks < 4; ++ks) {
                bf16x8 bb = ldB(wo1p, lane, ks, nf, 8);
                tf[nfl] = __builtin_amdgcn_mfma_f32_16x16x32_bf16(aA[ks], bb, tf[nfl], 0, 0, 0);
            }
        }
#pragma unroll
        for (int nfl = 0; nfl < 2; ++nfl)
#pragma unroll
            for (int r = 0; r < 4; ++r) {
                int pix = rg + r;
                int c   = w*32 + nfl*16 + cl0;
                float bo_ = nfl ? bov1 : bov0;
                t_bf[(size_t)(b*HWP + pix0 + pix)*128 + c] = f2bf(fmaxf(tf[nfl][r] + bo_, 0.f));
            }
    }
}

// ---------------- conv3x3 as implicit-GEMM MFMA + gate blend (chunked pipeline) ----------------
__global__ __launch_bounds__(256, 1) void fusion_conv3(
    const ushort* __restrict__ t_bf, const ushort* __restrict__ gq_bf,
    const ushort* __restrict__ fc_bf, const ushort* __restrict__ wo2p,
    const float* __restrict__ bo2, const float* __restrict__ gate,
    float* __restrict__ out)
{
    __shared__ ushort halo[2][18*18*64];

    const int t = threadIdx.x, lane = t & 63, w = t >> 6;
    const int b = blockIdx.x >> 6;
    const int tile = blockIdx.x & 63;
    const int h0 = (tile >> 3) * 16;
    const int w0 = (tile & 7) * 16;

    const int c8   = (t & 7) * 8;
    const int cell0 = t >> 3;

    for (int i = cell0; i < 324; i += 32) {
        int r = i / 18, cc = i - r*18;
        int hs = h0 - 1 + r, wsr = w0 - 1 + cc;
        bf16x8 v = (bf16x8){0,0,0,0,0,0,0,0};
        if ((unsigned)hs < (unsigned)HGT && (unsigned)wsr < (unsigned)WID)
            v = *(const bf16x8*)(t_bf + ((size_t)(b*HWP + hs*WID + wsr)*128 + c8));
        *(bf16x8*)(&halo[0][(i*64 + c8) ^ ((cc & 7) << 3)]) = v;
    }
    bf16x8 stg[11];
#pragma unroll
    for (int j = 0; j < 11; ++j) {
        int i = cell0 + 32*j;
        if (i < 324) {
            int r = i / 18, cc = i - r*18;
            int hs = h0 - 1 + r, wsr = w0 - 1 + cc;
            bf16x8 v = (bf16x8){0,0,0,0,0,0,0,0};
            if ((unsigned)hs < (unsigned)HGT && (unsigned)wsr < (unsigned)WID)
                v = *(const bf16x8*)(t_bf + ((size_t)(b*HWP + hs*WID + wsr)*128 + 64 + c8));
            stg[j] = v;
        }
    }
    __syncthreads();

    f32x4 acc[4][8];
#pragma unroll
    for (int mi = 0; mi < 4; ++mi)
#pragma unroll
        for (int nf = 0; nf < 8; ++nf) acc[mi][nf] = (f32x4){0.f,0.f,0.f,0.f};

    const int mcol = lane & 15;
    const int koff = (lane >> 4) << 3;

#pragma unroll 1
    for (int k = 0; k < 2; ++k) {
#pragma unroll 1
        for (int tap = 0; tap < 9; ++tap) {
            const int dy = tap / 3, dx = tap - dy*3;
            const int col = mcol + dx;
            const int swz = (col & 7) << 3;
#pragma unroll
            for (int ks2 = 0; ks2 < 2; ++ks2) {
                bf16x8 Bf[8];
#pragma unroll
                for (int nf = 0; nf < 8; ++nf)
                    Bf[nf] = *(const bf16x8*)(wo2p + (((size_t)((tap*4 + k*2 + ks2)*8 + nf))*64 + lane)*8);
#pragma unroll
                for (int mi = 0; mi < 4; ++mi) {
                    int mf = w*4 + mi;
                    int idx = (((mf + dy)*18 + col)*64 + ks2*32 + koff) ^ swz;
                    bf16x8 Af = *(const bf16x8*)(&halo[k][idx]);
#pragma unroll
                    for (int nf = 0; nf < 8; ++nf)
                        acc[mi][nf] = __builtin_amdgcn_mfma_f32_16x16x32_bf16(Af, Bf[nf], acc[mi][nf], 0, 0, 0);
                }
            }
        }
        if (k == 0) {
#pragma unroll
            for (int j = 0; j < 11; ++j) {
                int i = cell0 + 32*j;
                if (i < 324) {
                    int cc = i % 18;
                    *(bf16x8*)(&halo[1][(i*64 + c8) ^ ((cc & 7) << 3)]) = stg[j];
                }
            }
            __syncthreads();
        }
    }
    __syncthreads();

    float* fbuf = (float*)halo;
    const int cl0 = lane & 15;
    const int rg  = (lane >> 4) << 2;
    const int c_l = t & 63;
    const int rgw = (t >> 6) * 4;
#pragma unroll 1
    for (int nfg = 0; nfg < 2; ++nfg) {
#pragma unroll
        for (int mi = 0; mi < 4; ++mi)
#pragma unroll
            for (int nl = 0; nl < 4; ++nl) {
                int nf = nfg*4 + nl;
                int pix = (w*4 + mi)*16 + rg;
                *(f32x4*)(fbuf + (nl*16 + cl0)*260 + pix) = acc[mi][nf];
            }
        __syncthreads();
        {
            const int c  = nfg*64 + c_l;
            const float gt  = gate[b*CH + c];
            const float gti = 1.0f - gt;
            const float b2v = bo2[c];
#pragma unroll
            for (int rr = 0; rr < 4; ++rr) {
                int row = rgw + rr;
                const int gbase = (b*CH + c)*HWP + (h0 + row)*WID + w0;
                float vv[16];
#pragma unroll
                for (int q = 0; q < 2; ++q) {
                    f32x4 cv0 = *(const f32x4*)(fbuf + c_l*260 + row*16 + q*8);
                    f32x4 cv1 = *(const f32x4*)(fbuf + c_l*260 + row*16 + q*8 + 4);
                    bf16x8 gq8 = *(const bf16x8*)(gq_bf + gbase + q*8);
                    bf16x8 fc8 = *(const bf16x8*)(fc_bf + gbase + q*8);
#pragma unroll
                    for (int jj = 0; jj < 4; ++jj) {
                        vv[q*8+jj]   = gt*(cv0[jj] + b2v + bf2f((ushort)gq8[jj]))   + gti*bf2f((ushort)fc8[jj]);
                        vv[q*8+4+jj] = gt*(cv1[jj] + b2v + bf2f((ushort)gq8[4+jj])) + gti*bf2f((ushort)fc8[4+jj]);
                    }
                }
                float* od = out + gbase;
                *(float4*)(od)      = (float4){vv[0],vv[1],vv[2],vv[3]};
                *(float4*)(od + 4)  = (float4){vv[4],vv[5],vv[6],vv[7]};
                *(float4*)(od + 8)  = (float4){vv[8],vv[9],vv[10],vv[11]};
                *(float4*)(od + 12) = (float4){vv[12],vv[13],vv[14],vv[15]};
            }
        }
        __syncthreads();
    }
}

extern "C" void kernel_launch(void* const* d_in, const int* in_sizes, int n_in,
                              void* d_out, int out_size, void* d_ws, size_t ws_size,
                              hipStream_t stream)
{
    const float* bev = (const float*)d_in[0];
    const float* snr = (const float*)d_in[1];
    const float* vr  = (const float*)d_in[2];
    const float* Wq  = (const float*)d_in[3];
    const float* bq  = (const float*)d_in[4];
    const float* Wk  = (const float*)d_in[5];
    const float* bk  = (const float*)d_in[6];
    const float* Wv  = (const float*)d_in[7];
    const float* bv  = (const float*)d_in[8];
    const float* Wo1 = (const float*)d_in[9];
    const float* bo1 = (const float*)d_in[10];
    const float* Wo2 = (const float*)d_in[11];
    const float* bo2 = (const float*)d_in[12];
    const float* Wc1 = (const float*)d_in[13];
    const float* bc1 = (const float*)d_in[14];
    const float* Wc2 = (const float*)d_in[15];
    const float* bc2 = (const float*)d_in[16];
    const float* Wg  = (const float*)d_in[17];
    const float* bg  = (const float*)d_in[18];
    const float* Wr1 = (const float*)d_in[19];
    const float* br1 = (const float*)d_in[20];
    const float* Wr2 = (const float*)d_in[21];
    const float* br2 = (const float*)d_in[22];

    char* wsb = (char*)d_ws;
    ushort* t_bf  = (ushort*)(wsb);                       // 16 MB
    ushort* gq_bf = (ushort*)(wsb + 16777216);            // 16 MB
    ushort* fc_bf = (ushort*)(wsb + 33554432);            // 16 MB
    ushort* wqp   = (ushort*)(wsb + 50331648);
    ushort* wkp   = wqp + 16384;
    ushort* wvp   = wkp + 16384;
    ushort* wo1p  = wvp + 16384;
    ushort* wc1p  = wo1p + 16384;
    ushort* wo2p  = wc1p + 4096;                          // 147,456 ushorts
    float*  gate  = (float*)(wsb + 50331648 + 434176);
    float*  relb  = gate + 512;

    float* outp   = (float*)d_out;
    float* attn_o = outp + 8388608;
    float* conf_o = outp + 8781824;

    fusion_setup<<<2, 256, 0, stream>>>(snr, vr, Wg, bg, Wr1, br1, Wr2, br2,
                                        relb, gate);
    pack_weights<<<106, 256, 0, stream>>>(Wq, Wk, Wv, Wo1, Wc1, Wo2,
                                          wqp, wkp, wvp, wo1p, wc1p, wo2p);
    fusion_attn<<<4096, 256, 0, stream>>>(bev, wqp, wkp, wvp, wo1p, wc1p,
                                          bq, bk, bv, bo1, bc1, bc2, Wc2, relb,
                                          gq_bf, t_bf, fc_bf, attn_o, conf_o);
    fusion_conv3<<<256, 256, 0, stream>>>(t_bf, gq_bf, fc_bf, wo2p, bo2, gate, outp);
}

// Round 2
// 184.854 us; speedup vs baseline: 1.3111x; 1.3111x over previous
//
#include <hip/hip_runtime.h>
#include <hip/hip_bf16.h>
#include <math.h>

// Round 13: revert to R11 structure (TP=32, 147us known-good) after R12's
// TP=16 occupancy experiment regressed (per-block fixed costs doubled,
// partial-line RMW write amplification). Single change vs R11:
//   - hoist the loop-invariant B (weight) fragments for Wq/Wk/Wv into
//     registers BEFORE the 6-view loops (compiler provably wasn't CSE-ing:
//     VGPR=84/40 too low to hold them). Hot loops become pure ds_read+MFMA;
//     removes ~120 VMEM loads + vmcnt stalls per wave from the critical path.
// B=4 N=6 C=128 H=W=128, HEADS=4 HD=32 MID=32.

#define BB   4
#define NV   6
#define CH   128
#define HGT  128
#define WID  128
#define MIDD 32
#define HWP  (HGT*WID)
#define TP   32

#define SWZ(pix) (((pix) & 15) << 3)

typedef __attribute__((ext_vector_type(8))) short bf16x8;
typedef __attribute__((ext_vector_type(4))) float f32x4;

union U8 { bf16x8 v; unsigned u[4]; };

__device__ __forceinline__ ushort f2bf(float f) {
    union { __hip_bfloat16 h; ushort u; } v;
    v.h = __float2bfloat16(f);
    return v.u;
}
__device__ __forceinline__ float bf2f(ushort u) {
    return __uint_as_float(((unsigned)u) << 16);
}
__device__ __forceinline__ unsigned cvt_pk_bf16(float lo, float hi) {
    unsigned r;
    asm("v_cvt_pk_bf16_f32 %0, %1, %2" : "=v"(r) : "v"(lo), "v"(hi));
    return r;
}

// ---------------- setup: rel_bias, gate ----------------
__global__ void fusion_setup(const float* __restrict__ snr, const float* __restrict__ vr,
                             const float* __restrict__ Wg, const float* __restrict__ bg,
                             const float* __restrict__ Wr1, const float* __restrict__ br1,
                             const float* __restrict__ Wr2, const float* __restrict__ br2,
                             float* __restrict__ relb, float* __restrict__ gate)
{
    int tid = blockIdx.x * blockDim.x + threadIdx.x;
    if (tid < BB*CH) {
        int b = tid >> 7, c = tid & 127;
        float s = snr[b] * 0.05f;
        s = fminf(fmaxf(s, -1.5f), 1.5f);
        float z = s * Wg[c] + bg[c];
        gate[tid] = 1.0f / (1.0f + __expf(-z));
    }
    if (tid < BB*NV) {
        int b = tid / NV, n = tid % NV;
        float v0 = vr[(b*NV+n)*3+0], v1 = vr[(b*NV+n)*3+1], v2 = vr[(b*NV+n)*3+2];
        float acc = br2[0];
        for (int j = 0; j < MIDD; ++j) {
            float h = Wr1[j*3+0]*v0 + Wr1[j*3+1]*v1 + Wr1[j*3+2]*v2 + br1[j];
            acc += Wr2[j] * fmaxf(h, 0.0f);
        }
        relb[tid] = acc;
    }
}

// ---------------- weight frag-packing ----------------
__global__ void pack_weights(const float* __restrict__ Wq, const float* __restrict__ Wk,
                             const float* __restrict__ Wv, const float* __restrict__ Wo1,
                             const float* __restrict__ Wc1, const float* __restrict__ Wo2,
                             ushort* __restrict__ wqp, ushort* __restrict__ wkp,
                             ushort* __restrict__ wvp, ushort* __restrict__ wo1p,
                             ushort* __restrict__ wc1p, ushort* __restrict__ wo2p)
{
    int tid = blockIdx.x * 256 + threadIdx.x;
    if (tid >= 27136) return;
    if (tid < 8192) {
        int m = tid >> 11;
        int local = tid & 2047;
        const float* src = (m == 0) ? Wq : (m == 1) ? Wk : (m == 2) ? Wv : Wo1;
        ushort* dst = (m == 0) ? wqp : (m == 1) ? wkp : (m == 2) ? wvp : wo1p;
        int ks = local >> 9, rem = local & 511;
        int nf = rem >> 6, lane = rem & 63;
        int o = nf*16 + (lane & 15);
        int i0 = ks*32 + ((lane >> 4) << 3);
        const float* s = src + o*CH + i0;
        ushort* d = dst + local*8;
#pragma unroll
        for (int j = 0; j < 8; ++j) d[j] = f2bf(s[j]);
    } else if (tid < 8704) {
        int local = tid - 8192;
        int ks = local >> 7, rem = local & 127;
        int nf = rem >> 6, lane = rem & 63;
        int o = nf*16 + (lane & 15);
        int i0 = ks*32 + ((lane >> 4) << 3);
        const float* s = Wc1 + o*CH + i0;
        ushort* d = wc1p + local*8;
#pragma unroll
        for (int j = 0; j < 8; ++j) d[j] = f2bf(s[j]);
    } else {
        int l2 = tid - 8704;
        int lane = l2 & 63;
        int rest = l2 >> 6;
        int nf = rest & 7;
        int kst = rest >> 3;
        int ks = kst & 3;
        int tap = kst >> 2;
        int co = nf*16 + (lane & 15);
        int ci0 = ks*32 + ((lane >> 4) << 3);
        ushort* d = wo2p + l2*8;
#pragma unroll
        for (int j = 0; j < 8; ++j) d[j] = f2bf(Wo2[(co*CH + ci0 + j)*9 + tap]);
    }
}

// ---------------- MFMA helpers ----------------
__device__ __forceinline__ bf16x8 ldsA(const ushort* tile, int lane, int mf, int ks) {
    int pix = mf*16 + (lane & 15);
    int idx = (pix*128 + ks*32 + ((lane >> 4) << 3)) ^ SWZ(pix);
    return *(const bf16x8*)(tile + idx);
}
__device__ __forceinline__ bf16x8 ldB(const ushort* pack, int lane, int ks, int nf, int NF) {
    return *(const bf16x8*)(pack + (((ks*NF + nf)*64) + lane)*8);
}

// ---------------- fusion_attn: per (b, 32-pix tile) ----------------
__global__ __launch_bounds__(256, 3) void fusion_attn(
    const float* __restrict__ bev,
    const ushort* __restrict__ wqp, const ushort* __restrict__ wkp,
    const ushort* __restrict__ wvp, const ushort* __restrict__ wo1p,
    const ushort* __restrict__ wc1p,
    const float* __restrict__ bq, const float* __restrict__ bk,
    const float* __restrict__ bv, const float* __restrict__ bo1,
    const float* __restrict__ bc1, const float* __restrict__ bc2,
    const float* __restrict__ Wc2, const float* __restrict__ relb,
    ushort* __restrict__ gq_bf, ushort* __restrict__ t_bf, ushort* __restrict__ fc_bf,
    float* __restrict__ attn_o, float* __restrict__ conf_o)
{
    __shared__ ushort xt[NV][TP*128];   // swizzled [pix][c] bf16; xt[0] reused for fused
    __shared__ float  scat[NV][4][TP];
    __shared__ float  lpart[NV][TP];
    __shared__ float  cfw[NV][TP];

    const int t = threadIdx.x, lane = t & 63, w = t >> 6;
    const int b = blockIdx.x >> 9;
    const int pix0 = (blockIdx.x & 511) * TP;

    // ---- Phase A: stage 6 views -> LDS bf16 swizzled; 3-view-deep load pipeline ----
    const int pixg = (t & 3) * 8;
    const int c0   = (t >> 2) * 2;
    const float* sb = bev + (((size_t)b*NV*CH + c0)*HWP + pix0 + pixg);
    const size_t vstep = (size_t)CH*HWP;
    float gacc[16];
#pragma unroll
    for (int i = 0; i < 16; ++i) gacc[i] = 0.f;
    float4 L[3][4];                      // rotating 3-view buffer (fully-unrolled static idx)
#pragma unroll
    for (int j = 0; j < 3; ++j) {
        const float* s1 = sb + (size_t)j*vstep;
        L[j][0] = *(const float4*)(s1);
        L[j][1] = *(const float4*)(s1 + 4);
        L[j][2] = *(const float4*)(s1 + HWP);
        L[j][3] = *(const float4*)(s1 + HWP + 4);
    }
#pragma unroll
    for (int n = 0; n < NV; ++n) {
        const int slot = n % 3;          // static under full unroll
        float4 a0 = L[slot][0], a1 = L[slot][1], b0 = L[slot][2], b1 = L[slot][3];
        if (n + 3 < NV) {
            const float* s1 = sb + (size_t)(n+3)*vstep;
            L[slot][0] = *(const float4*)(s1);
            L[slot][1] = *(const float4*)(s1 + 4);
            L[slot][2] = *(const float4*)(s1 + HWP);
            L[slot][3] = *(const float4*)(s1 + HWP + 4);
        }
        float r0[8] = {a0.x,a0.y,a0.z,a0.w, a1.x,a1.y,a1.z,a1.w};
        float r1[8] = {b0.x,b0.y,b0.z,b0.w, b1.x,b1.y,b1.z,b1.w};
#pragma unroll
        for (int p = 0; p < 8; ++p) {
            int pix = pixg + p;
            unsigned pk = cvt_pk_bf16(r0[p], r1[p]);
            *(unsigned*)(&xt[n][(pix*128 + c0) ^ SWZ(pix)]) = pk;
            gacc[p]   += r0[p];
            gacc[8+p] += r1[p];
        }
    }
    {
        U8 g0, g1;
#pragma unroll
        for (int p = 0; p < 4; ++p) {
            g0.u[p] = cvt_pk_bf16(gacc[2*p]   * (1.0f/6.0f), gacc[2*p+1] * (1.0f/6.0f));
            g1.u[p] = cvt_pk_bf16(gacc[8+2*p] * (1.0f/6.0f), gacc[9+2*p] * (1.0f/6.0f));
        }
        ushort* gd = gq_bf + ((size_t)(b*CH + c0)*HWP + pix0 + pixg);
        *(bf16x8*)(gd)       = g0.v;
        *(bf16x8*)(gd + HWP) = g1.v;
    }
    __syncthreads();

    const int cl0 = (lane & 15);
    const int rg  = (lane >> 4) << 2;
    const float bqv0 = bq[w*32 + cl0],      bqv1 = bq[w*32 + 16 + cl0];
    const float bkv0 = bk[w*32 + cl0],      bkv1 = bk[w*32 + 16 + cl0];
    const float bvv0 = bv[w*32 + cl0],      bvv1 = bv[w*32 + 16 + cl0];
    const float bov0 = bo1[w*32 + cl0],     bov1 = bo1[w*32 + 16 + cl0];
    const float bc10 = bc1[cl0],            bc11 = bc1[16 + cl0];
    const float wc20 = Wc2[cl0],            wc21 = Wc2[16 + cl0];

    // ---- Pass 1: Q accumulated across views via MFMA; conf for assigned views ----
    f32x4 qf[2][2];
#pragma unroll
    for (int mf = 0; mf < 2; ++mf)
#pragma unroll
        for (int nfl = 0; nfl < 2; ++nfl) qf[mf][nfl] = (f32x4){0.f,0.f,0.f,0.f};
    // hoisted loop-invariant Wq fragments (load once, use 6x)
    bf16x8 Bq[2][4];
#pragma unroll
    for (int nfl = 0; nfl < 2; ++nfl)
#pragma unroll
        for (int ks = 0; ks < 4; ++ks) Bq[nfl][ks] = ldB(wqp, lane, ks, 2*w + nfl, 8);
#pragma unroll 2
    for (int n = 0; n < NV; ++n) {
        bf16x8 xA[2][4];
#pragma unroll
        for (int mf = 0; mf < 2; ++mf)
#pragma unroll
            for (int ks = 0; ks < 4; ++ks) xA[mf][ks] = ldsA(xt[n], lane, mf, ks);
#pragma unroll
        for (int nfl = 0; nfl < 2; ++nfl) {
#pragma unroll
            for (int ks = 0; ks < 4; ++ks) {
#pragma unroll
                for (int mf = 0; mf < 2; ++mf)
                    qf[mf][nfl] = __builtin_amdgcn_mfma_f32_16x16x32_bf16(xA[mf][ks], Bq[nfl][ks], qf[mf][nfl], 0, 0, 0);
            }
        }
        if (n == w || n == w + 4) {
            f32x4 cf[2][2];
#pragma unroll
            for (int mf = 0; mf < 2; ++mf)
#pragma unroll
                for (int nfc = 0; nfc < 2; ++nfc) cf[mf][nfc] = (f32x4){0.f,0.f,0.f,0.f};
#pragma unroll
            for (int nfc = 0; nfc < 2; ++nfc) {
#pragma unroll
                for (int ks = 0; ks < 4; ++ks) {
                    bf16x8 bb = ldB(wc1p, lane, ks, nfc, 2);
#pragma unroll
                    for (int mf = 0; mf < 2; ++mf)
                        cf[mf][nfc] = __builtin_amdgcn_mfma_f32_16x16x32_bf16(xA[mf][ks], bb, cf[mf][nfc], 0, 0, 0);
                }
            }
#pragma unroll
            for (int mf = 0; mf < 2; ++mf) {
#pragma unroll
                for (int r = 0; r < 4; ++r) {
                    float pl = fmaxf(cf[mf][0][r] + bc10, 0.f)*wc20
                             + fmaxf(cf[mf][1][r] + bc11, 0.f)*wc21;
                    pl += __shfl_xor(pl, 1, 64);
                    pl += __shfl_xor(pl, 2, 64);
                    pl += __shfl_xor(pl, 4, 64);
                    pl += __shfl_xor(pl, 8, 64);
                    if (cl0 == 0) lpart[n][mf*16 + rg + r] = pl;
                }
            }
        }
    }
#pragma unroll
    for (int mf = 0; mf < 2; ++mf)
#pragma unroll
        for (int r = 0; r < 4; ++r) {
            qf[mf][0][r] = qf[mf][0][r]*(1.0f/6.0f) + bqv0;
            qf[mf][1][r] = qf[mf][1][r]*(1.0f/6.0f) + bqv1;
        }

    // ---- Pass 2: K per view -> scores ----
    bf16x8 Bk[2][4];
#pragma unroll
    for (int nfl = 0; nfl < 2; ++nfl)
#pragma unroll
        for (int ks = 0; ks < 4; ++ks) Bk[nfl][ks] = ldB(wkp, lane, ks, 2*w + nfl, 8);
#pragma unroll 2
    for (int n = 0; n < NV; ++n) {
        bf16x8 xA[2][4];
#pragma unroll
        for (int mf = 0; mf < 2; ++mf)
#pragma unroll
            for (int ks = 0; ks < 4; ++ks) xA[mf][ks] = ldsA(xt[n], lane, mf, ks);
        f32x4 kf[2][2];
#pragma unroll
        for (int mf = 0; mf < 2; ++mf)
#pragma unroll
            for (int nfl = 0; nfl < 2; ++nfl) kf[mf][nfl] = (f32x4){0.f,0.f,0.f,0.f};
#pragma unroll
        for (int nfl = 0; nfl < 2; ++nfl) {
#pragma unroll
            for (int ks = 0; ks < 4; ++ks) {
#pragma unroll
                for (int mf = 0; mf < 2; ++mf)
                    kf[mf][nfl] = __builtin_amdgcn_mfma_f32_16x16x32_bf16(xA[mf][ks], Bk[nfl][ks], kf[mf][nfl], 0, 0, 0);
            }
        }
#pragma unroll
        for (int mf = 0; mf < 2; ++mf) {
#pragma unroll
            for (int r = 0; r < 4; ++r) {
                float s = qf[mf][0][r]*(kf[mf][0][r] + bkv0) + qf[mf][1][r]*(kf[mf][1][r] + bkv1);
                s += __shfl_xor(s, 1, 64);
                s += __shfl_xor(s, 2, 64);
                s += __shfl_xor(s, 4, 64);
                s += __shfl_xor(s, 8, 64);
                if (cl0 == 0) scat[n][w][mf*16 + rg + r] = s * 0.17677669529663687f;
            }
        }
    }
    __syncthreads();

    // ---- Phase D: attn softmax (t<128) || conf softmax (128<=t<160) ----
    if (t < 128) {
        int h = t >> 5, pix = t & 31;
        float s0 = scat[0][h][pix], s1 = scat[1][h][pix], s2 = scat[2][h][pix],
              s3 = scat[3][h][pix], s4 = scat[4][h][pix], s5 = scat[5][h][pix];
        float mx = fmaxf(fmaxf(fmaxf(s0,s1),fmaxf(s2,s3)),fmaxf(s4,s5));
        float e0=__expf(s0-mx), e1=__expf(s1-mx), e2=__expf(s2-mx),
              e3=__expf(s3-mx), e4=__expf(s4-mx), e5=__expf(s5-mx);
        float inv = 1.0f/(e0+e1+e2+e3+e4+e5);
        scat[0][h][pix]=e0*inv; scat[1][h][pix]=e1*inv; scat[2][h][pix]=e2*inv;
        scat[3][h][pix]=e3*inv; scat[4][h][pix]=e4*inv; scat[5][h][pix]=e5*inv;
    } else if (t < 160) {
        int pix = t - 128;
        float bc2v = bc2[0];
        float lg[NV];
#pragma unroll
        for (int n = 0; n < NV; ++n)
            lg[n] = lpart[n][pix] + bc2v + relb[b*NV + n];
        float mx = fmaxf(fmaxf(fmaxf(lg[0],lg[1]),fmaxf(lg[2],lg[3])),fmaxf(lg[4],lg[5]));
        float e[NV], sum = 0.f;
#pragma unroll
        for (int n = 0; n < NV; ++n) { e[n] = __expf(lg[n]-mx); sum += e[n]; }
        float inv = 1.0f/sum;
#pragma unroll
        for (int n = 0; n < NV; ++n) {
            float wv = e[n]*inv;
            cfw[n][pix] = wv;
            conf_o[(b*NV + n)*HWP + pix0 + pix] = wv;
        }
    }
    __syncthreads();

    // ---- Pass 3: V per view via MFMA, attn-scale C-regs ----
    f32x4 ff[2][2];
#pragma unroll
    for (int mf = 0; mf < 2; ++mf)
#pragma unroll
        for (int nfl = 0; nfl < 2; ++nfl) ff[mf][nfl] = (f32x4){0.f,0.f,0.f,0.f};
    bf16x8 Bv[2][4];
#pragma unroll
    for (int nfl = 0; nfl < 2; ++nfl)
#pragma unroll
        for (int ks = 0; ks < 4; ++ks) Bv[nfl][ks] = ldB(wvp, lane, ks, 2*w + nfl, 8);
#pragma unroll 2
    for (int n = 0; n < NV; ++n) {
        bf16x8 xA[2][4];
#pragma unroll
        for (int mf = 0; mf < 2; ++mf)
#pragma unroll
            for (int ks = 0; ks < 4; ++ks) xA[mf][ks] = ldsA(xt[n], lane, mf, ks);
        f32x4 vv[2][2];
#pragma unroll
        for (int mf = 0; mf < 2; ++mf)
#pragma unroll
            for (int nfl = 0; nfl < 2; ++nfl) vv[mf][nfl] = (f32x4){0.f,0.f,0.f,0.f};
#pragma unroll
        for (int nfl = 0; nfl < 2; ++nfl) {
#pragma unroll
            for (int ks = 0; ks < 4; ++ks) {
#pragma unroll
                for (int mf = 0; mf < 2; ++mf)
                    vv[mf][nfl] = __builtin_amdgcn_mfma_f32_16x16x32_bf16(xA[mf][ks], Bv[nfl][ks], vv[mf][nfl], 0, 0, 0);
            }
        }
#pragma unroll
        for (int mf = 0; mf < 2; ++mf) {
#pragma unroll
            for (int r = 0; r < 4; ++r) {
                float a = scat[n][w][mf*16 + rg + r];
                ff[mf][0][r] += a * vv[mf][0][r];
                ff[mf][1][r] += a * vv[mf][1][r];
            }
        }
    }
#pragma unroll
    for (int mf = 0; mf < 2; ++mf)
#pragma unroll
        for (int r = 0; r < 4; ++r) { ff[mf][0][r] += bvv0; ff[mf][1][r] += bvv1; }

    // ---- fc = sum_n cfw[n]*x_n -> fc_bf NCHW bf16 ----
    {
        float fcv[16];
#pragma unroll
        for (int i = 0; i < 16; ++i) fcv[i] = 0.f;
#pragma unroll
        for (int n = 0; n < NV; ++n) {
#pragma unroll
            for (int p = 0; p < 8; ++p) {
                int pix = pixg + p;
                float cwv = cfw[n][pix];
                unsigned pk = *(const unsigned*)(&xt[n][(pix*128 + c0) ^ SWZ(pix)]);
                fcv[p]   += cwv * bf2f((ushort)(pk & 0xffffu));
                fcv[8+p] += cwv * bf2f((ushort)(pk >> 16));
            }
        }
        U8 f0, f1;
#pragma unroll
        for (int p = 0; p < 4; ++p) {
            f0.u[p] = cvt_pk_bf16(fcv[2*p],   fcv[2*p+1]);
            f1.u[p] = cvt_pk_bf16(fcv[8+2*p], fcv[9+2*p]);
        }
        ushort* fd = fc_bf + ((size_t)(b*CH + c0)*HWP + pix0 + pixg);
        *(bf16x8*)(fd)       = f0.v;
        *(bf16x8*)(fd + HWP) = f1.v;
    }
    if (t < 192) {
        int n = t >> 5, pix = t & 31;
        float am = 0.25f*(scat[n][0][pix]+scat[n][1][pix]+scat[n][2][pix]+scat[n][3][pix]);
        attn_o[(b*NV + n)*HWP + pix0 + pix] = am;
    }
    __syncthreads();

    // ---- fused frags -> xt[0] (swizzled) ----
    {
        ushort* xt0 = &xt[0][0];
#pragma unroll
        for (int mf = 0; mf < 2; ++mf)
#pragma unroll
            for (int nfl = 0; nfl < 2; ++nfl)
#pragma unroll
                for (int r = 0; r < 4; ++r) {
                    int pix = mf*16 + rg + r;
                    int c   = w*32 + nfl*16 + cl0;
                    xt0[(pix*128 + c) ^ SWZ(pix)] = f2bf(ff[mf][nfl][r]);
                }
    }
    __syncthreads();

    // ---- Phase F: t = relu(Wo1 @ fused + bo1) -> t_bf NHWC bf16 ----
    {
        bf16x8 aA[2][4];
#pragma unroll
        for (int mf = 0; mf < 2; ++mf)
#pragma unroll
            for (int ks = 0; ks < 4; ++ks) aA[mf][ks] = ldsA(&xt[0][0], lane, mf, ks);
        f32x4 tf[2][2];
#pragma unroll
        for (int mf = 0; mf < 2; ++mf)
#pragma unroll
            for (int nfl = 0; nfl < 2; ++nfl) tf[mf][nfl] = (f32x4){0.f,0.f,0.f,0.f};
#pragma unroll
        for (int nfl = 0; nfl < 2; ++nfl) {
            int nf = 2*w + nfl;
#pragma unroll
            for (int ks = 0; ks < 4; ++ks) {
                bf16x8 bb = ldB(wo1p, lane, ks, nf, 8);
#pragma unroll
                for (int mf = 0; mf < 2; ++mf)
                    tf[mf][nfl] = __builtin_amdgcn_mfma_f32_16x16x32_bf16(aA[mf][ks], bb, tf[mf][nfl], 0, 0, 0);
            }
        }
#pragma unroll
        for (int mf = 0; mf < 2; ++mf)
#pragma unroll
            for (int nfl = 0; nfl < 2; ++nfl)
#pragma unroll
                for (int r = 0; r < 4; ++r) {
                    int pix = mf*16 + rg + r;
                    int c   = w*32 + nfl*16 + cl0;
                    float bo_ = nfl ? bov1 : bov0;
                    t_bf[(size_t)(b*HWP + pix0 + pix)*128 + c] = f2bf(fmaxf(tf[mf][nfl][r] + bo_, 0.f));
                }
    }
}

// ---------------- conv3x3 as implicit-GEMM MFMA + gate blend (chunked pipeline) ----------------
__global__ __launch_bounds__(256, 1) void fusion_conv3(
    const ushort* __restrict__ t_bf, const ushort* __restrict__ gq_bf,
    const ushort* __restrict__ fc_bf, const ushort* __restrict__ wo2p,
    const float* __restrict__ bo2, const float* __restrict__ gate,
    float* __restrict__ out)
{
    __shared__ ushort halo[2][18*18*64];

    const int t = threadIdx.x, lane = t & 63, w = t >> 6;
    const int b = blockIdx.x >> 6;
    const int tile = blockIdx.x & 63;
    const int h0 = (tile >> 3) * 16;
    const int w0 = (tile & 7) * 16;

    const int c8   = (t & 7) * 8;
    const int cell0 = t >> 3;

    for (int i = cell0; i < 324; i += 32) {
        int r = i / 18, cc = i - r*18;
        int hs = h0 - 1 + r, wsr = w0 - 1 + cc;
        bf16x8 v = (bf16x8){0,0,0,0,0,0,0,0};
        if ((unsigned)hs < (unsigned)HGT && (unsigned)wsr < (unsigned)WID)
            v = *(const bf16x8*)(t_bf + ((size_t)(b*HWP + hs*WID + wsr)*128 + c8));
        *(bf16x8*)(&halo[0][(i*64 + c8) ^ ((cc & 7) << 3)]) = v;
    }
    bf16x8 stg[11];
#pragma unroll
    for (int j = 0; j < 11; ++j) {
        int i = cell0 + 32*j;
        if (i < 324) {
            int r = i / 18, cc = i - r*18;
            int hs = h0 - 1 + r, wsr = w0 - 1 + cc;
            bf16x8 v = (bf16x8){0,0,0,0,0,0,0,0};
            if ((unsigned)hs < (unsigned)HGT && (unsigned)wsr < (unsigned)WID)
                v = *(const bf16x8*)(t_bf + ((size_t)(b*HWP + hs*WID + wsr)*128 + 64 + c8));
            stg[j] = v;
        }
    }
    __syncthreads();

    f32x4 acc[4][8];
#pragma unroll
    for (int mi = 0; mi < 4; ++mi)
#pragma unroll
        for (int nf = 0; nf < 8; ++nf) acc[mi][nf] = (f32x4){0.f,0.f,0.f,0.f};

    const int mcol = lane & 15;
    const int koff = (lane >> 4) << 3;

#pragma unroll 1
    for (int k = 0; k < 2; ++k) {
#pragma unroll 1
        for (int tap = 0; tap < 9; ++tap) {
            const int dy = tap / 3, dx = tap - dy*3;
            const int col = mcol + dx;
            const int swz = (col & 7) << 3;
#pragma unroll
            for (int ks2 = 0; ks2 < 2; ++ks2) {
                bf16x8 Bf[8];
#pragma unroll
                for (int nf = 0; nf < 8; ++nf)
                    Bf[nf] = *(const bf16x8*)(wo2p + (((size_t)((tap*4 + k*2 + ks2)*8 + nf))*64 + lane)*8);
#pragma unroll
                for (int mi = 0; mi < 4; ++mi) {
                    int mf = w*4 + mi;
                    int idx = (((mf + dy)*18 + col)*64 + ks2*32 + koff) ^ swz;
                    bf16x8 Af = *(const bf16x8*)(&halo[k][idx]);
#pragma unroll
                    for (int nf = 0; nf < 8; ++nf)
                        acc[mi][nf] = __builtin_amdgcn_mfma_f32_16x16x32_bf16(Af, Bf[nf], acc[mi][nf], 0, 0, 0);
                }
            }
        }
        if (k == 0) {
#pragma unroll
            for (int j = 0; j < 11; ++j) {
                int i = cell0 + 32*j;
                if (i < 324) {
                    int cc = i % 18;
                    *(bf16x8*)(&halo[1][(i*64 + c8) ^ ((cc & 7) << 3)]) = stg[j];
                }
            }
            __syncthreads();
        }
    }
    __syncthreads();

    float* fbuf = (float*)halo;
    const int cl0 = lane & 15;
    const int rg  = (lane >> 4) << 2;
    const int c_l = t & 63;
    const int rgw = (t >> 6) * 4;
#pragma unroll 1
    for (int nfg = 0; nfg < 2; ++nfg) {
#pragma unroll
        for (int mi = 0; mi < 4; ++mi)
#pragma unroll
            for (int nl = 0; nl < 4; ++nl) {
                int nf = nfg*4 + nl;
                int pix = (w*4 + mi)*16 + rg;
                *(f32x4*)(fbuf + (nl*16 + cl0)*260 + pix) = acc[mi][nf];
            }
        __syncthreads();
        {
            const int c  = nfg*64 + c_l;
            const float gt  = gate[b*CH + c];
            const float gti = 1.0f - gt;
            const float b2v = bo2[c];
#pragma unroll
            for (int rr = 0; rr < 4; ++rr) {
                int row = rgw + rr;
                const int gbase = (b*CH + c)*HWP + (h0 + row)*WID + w0;
                float vv[16];
#pragma unroll
                for (int q = 0; q < 2; ++q) {
                    f32x4 cv0 = *(const f32x4*)(fbuf + c_l*260 + row*16 + q*8);
                    f32x4 cv1 = *(const f32x4*)(fbuf + c_l*260 + row*16 + q*8 + 4);
                    bf16x8 gq8 = *(const bf16x8*)(gq_bf + gbase + q*8);
                    bf16x8 fc8 = *(const bf16x8*)(fc_bf + gbase + q*8);
#pragma unroll
                    for (int jj = 0; jj < 4; ++jj) {
                        vv[q*8+jj]   = gt*(cv0[jj] + b2v + bf2f((ushort)gq8[jj]))   + gti*bf2f((ushort)fc8[jj]);
                        vv[q*8+4+jj] = gt*(cv1[jj] + b2v + bf2f((ushort)gq8[4+jj])) + gti*bf2f((ushort)fc8[4+jj]);
                    }
                }
                float* od = out + gbase;
                *(float4*)(od)      = (float4){vv[0],vv[1],vv[2],vv[3]};
                *(float4*)(od + 4)  = (float4){vv[4],vv[5],vv[6],vv[7]};
                *(float4*)(od + 8)  = (float4){vv[8],vv[9],vv[10],vv[11]};
                *(float4*)(od + 12) = (float4){vv[12],vv[13],vv[14],vv[15]};
            }
        }
        __syncthreads();
    }
}

extern "C" void kernel_launch(void* const* d_in, const int* in_sizes, int n_in,
                              void* d_out, int out_size, void* d_ws, size_t ws_size,
                              hipStream_t stream)
{
    const float* bev = (const float*)d_in[0];
    const float* snr = (const float*)d_in[1];
    const float* vr  = (const float*)d_in[2];
    const float* Wq  = (const float*)d_in[3];
    const float* bq  = (const float*)d_in[4];
    const float* Wk  = (const float*)d_in[5];
    const float* bk  = (const float*)d_in[6];
    const float* Wv  = (const float*)d_in[7];
    const float* bv  = (const float*)d_in[8];
    const float* Wo1 = (const float*)d_in[9];
    const float* bo1 = (const float*)d_in[10];
    const float* Wo2 = (const float*)d_in[11];
    const float* bo2 = (const float*)d_in[12];
    const float* Wc1 = (const float*)d_in[13];
    const float* bc1 = (const float*)d_in[14];
    const float* Wc2 = (const float*)d_in[15];
    const float* bc2 = (const float*)d_in[16];
    const float* Wg  = (const float*)d_in[17];
    const float* bg  = (const float*)d_in[18];
    const float* Wr1 = (const float*)d_in[19];
    const float* br1 = (const float*)d_in[20];
    const float* Wr2 = (const float*)d_in[21];
    const float* br2 = (const float*)d_in[22];

    char* wsb = (char*)d_ws;
    ushort* t_bf  = (ushort*)(wsb);                       // 16 MB
    ushort* gq_bf = (ushort*)(wsb + 16777216);            // 16 MB
    ushort* fc_bf = (ushort*)(wsb + 33554432);            // 16 MB
    ushort* wqp   = (ushort*)(wsb + 50331648);
    ushort* wkp   = wqp + 16384;
    ushort* wvp   = wkp + 16384;
    ushort* wo1p  = wvp + 16384;
    ushort* wc1p  = wo1p + 16384;
    ushort* wo2p  = wc1p + 4096;                          // 147,456 ushorts
    float*  gate  = (float*)(wsb + 50331648 + 434176);
    float*  relb  = gate + 512;

    float* outp   = (float*)d_out;
    float* attn_o = outp + 8388608;
    float* conf_o = outp + 8781824;

    fusion_setup<<<2, 256, 0, stream>>>(snr, vr, Wg, bg, Wr1, br1, Wr2, br2,
                                        relb, gate);
    pack_weights<<<106, 256, 0, stream>>>(Wq, Wk, Wv, Wo1, Wc1, Wo2,
                                          wqp, wkp, wvp, wo1p, wc1p, wo2p);
    fusion_attn<<<2048, 256, 0, stream>>>(bev, wqp, wkp, wvp, wo1p, wc1p,
                                          bq, bk, bv, bo1, bc1, bc2, Wc2, relb,
                                          gq_bf, t_bf, fc_bf, attn_o, conf_o);
    fusion_conv3<<<256, 256, 0, stream>>>(t_bf, gq_bf, fc_bf, wo2p, bo2, gate, outp);
}

// Round 3
// 178.735 us; speedup vs baseline: 1.3560x; 1.0342x over previous
//
#include <hip/hip_runtime.h>
#include <hip/hip_bf16.h>
#include <math.h>

// Round 14: attack the diagnosed limiter — Phase-A gather latency.
// Evidence: R10-R13 all ~147us regardless of inner-loop changes; FETCH ~100MB
// at ~700 GB/s read in every variant => load-wait dominated, MFMA passes are
// hidden behind it. Two changes vs R13 (structure otherwise identical):
//   (1) issue ALL 24 phase-A global loads up front (6-view-deep pipeline,
//       L[6][4], static idx) -> 2x per-wave VMEM in flight (12->24 insts).
//   (2) bijective XCD swizzle on the 2048 blocks (2048%8==0): adjacent pixel
//       tiles share an XCD => gq/fc 64B half-line writes pair up within one
//       L2 => no cross-XCD partial-line RMW.
// B=4 N=6 C=128 H=W=128, HEADS=4 HD=32 MID=32.

#define BB   4
#define NV   6
#define CH   128
#define HGT  128
#define WID  128
#define MIDD 32
#define HWP  (HGT*WID)
#define TP   32

#define SWZ(pix) (((pix) & 15) << 3)

typedef __attribute__((ext_vector_type(8))) short bf16x8;
typedef __attribute__((ext_vector_type(4))) float f32x4;

union U8 { bf16x8 v; unsigned u[4]; };

__device__ __forceinline__ ushort f2bf(float f) {
    union { __hip_bfloat16 h; ushort u; } v;
    v.h = __float2bfloat16(f);
    return v.u;
}
__device__ __forceinline__ float bf2f(ushort u) {
    return __uint_as_float(((unsigned)u) << 16);
}
__device__ __forceinline__ unsigned cvt_pk_bf16(float lo, float hi) {
    unsigned r;
    asm("v_cvt_pk_bf16_f32 %0, %1, %2" : "=v"(r) : "v"(lo), "v"(hi));
    return r;
}

// ---------------- setup: rel_bias, gate ----------------
__global__ void fusion_setup(const float* __restrict__ snr, const float* __restrict__ vr,
                             const float* __restrict__ Wg, const float* __restrict__ bg,
                             const float* __restrict__ Wr1, const float* __restrict__ br1,
                             const float* __restrict__ Wr2, const float* __restrict__ br2,
                             float* __restrict__ relb, float* __restrict__ gate)
{
    int tid = blockIdx.x * blockDim.x + threadIdx.x;
    if (tid < BB*CH) {
        int b = tid >> 7, c = tid & 127;
        float s = snr[b] * 0.05f;
        s = fminf(fmaxf(s, -1.5f), 1.5f);
        float z = s * Wg[c] + bg[c];
        gate[tid] = 1.0f / (1.0f + __expf(-z));
    }
    if (tid < BB*NV) {
        int b = tid / NV, n = tid % NV;
        float v0 = vr[(b*NV+n)*3+0], v1 = vr[(b*NV+n)*3+1], v2 = vr[(b*NV+n)*3+2];
        float acc = br2[0];
        for (int j = 0; j < MIDD; ++j) {
            float h = Wr1[j*3+0]*v0 + Wr1[j*3+1]*v1 + Wr1[j*3+2]*v2 + br1[j];
            acc += Wr2[j] * fmaxf(h, 0.0f);
        }
        relb[tid] = acc;
    }
}

// ---------------- weight frag-packing ----------------
__global__ void pack_weights(const float* __restrict__ Wq, const float* __restrict__ Wk,
                             const float* __restrict__ Wv, const float* __restrict__ Wo1,
                             const float* __restrict__ Wc1, const float* __restrict__ Wo2,
                             ushort* __restrict__ wqp, ushort* __restrict__ wkp,
                             ushort* __restrict__ wvp, ushort* __restrict__ wo1p,
                             ushort* __restrict__ wc1p, ushort* __restrict__ wo2p)
{
    int tid = blockIdx.x * 256 + threadIdx.x;
    if (tid >= 27136) return;
    if (tid < 8192) {
        int m = tid >> 11;
        int local = tid & 2047;
        const float* src = (m == 0) ? Wq : (m == 1) ? Wk : (m == 2) ? Wv : Wo1;
        ushort* dst = (m == 0) ? wqp : (m == 1) ? wkp : (m == 2) ? wvp : wo1p;
        int ks = local >> 9, rem = local & 511;
        int nf = rem >> 6, lane = rem & 63;
        int o = nf*16 + (lane & 15);
        int i0 = ks*32 + ((lane >> 4) << 3);
        const float* s = src + o*CH + i0;
        ushort* d = dst + local*8;
#pragma unroll
        for (int j = 0; j < 8; ++j) d[j] = f2bf(s[j]);
    } else if (tid < 8704) {
        int local = tid - 8192;
        int ks = local >> 7, rem = local & 127;
        int nf = rem >> 6, lane = rem & 63;
        int o = nf*16 + (lane & 15);
        int i0 = ks*32 + ((lane >> 4) << 3);
        const float* s = Wc1 + o*CH + i0;
        ushort* d = wc1p + local*8;
#pragma unroll
        for (int j = 0; j < 8; ++j) d[j] = f2bf(s[j]);
    } else {
        int l2 = tid - 8704;
        int lane = l2 & 63;
        int rest = l2 >> 6;
        int nf = rest & 7;
        int kst = rest >> 3;
        int ks = kst & 3;
        int tap = kst >> 2;
        int co = nf*16 + (lane & 15);
        int ci0 = ks*32 + ((lane >> 4) << 3);
        ushort* d = wo2p + l2*8;
#pragma unroll
        for (int j = 0; j < 8; ++j) d[j] = f2bf(Wo2[(co*CH + ci0 + j)*9 + tap]);
    }
}

// ---------------- MFMA helpers ----------------
__device__ __forceinline__ bf16x8 ldsA(const ushort* tile, int lane, int mf, int ks) {
    int pix = mf*16 + (lane & 15);
    int idx = (pix*128 + ks*32 + ((lane >> 4) << 3)) ^ SWZ(pix);
    return *(const bf16x8*)(tile + idx);
}
__device__ __forceinline__ bf16x8 ldB(const ushort* pack, int lane, int ks, int nf, int NF) {
    return *(const bf16x8*)(pack + (((ks*NF + nf)*64) + lane)*8);
}

// ---------------- fusion_attn: per (b, 32-pix tile) ----------------
__global__ __launch_bounds__(256, 3) void fusion_attn(
    const float* __restrict__ bev,
    const ushort* __restrict__ wqp, const ushort* __restrict__ wkp,
    const ushort* __restrict__ wvp, const ushort* __restrict__ wo1p,
    const ushort* __restrict__ wc1p,
    const float* __restrict__ bq, const float* __restrict__ bk,
    const float* __restrict__ bv, const float* __restrict__ bo1,
    const float* __restrict__ bc1, const float* __restrict__ bc2,
    const float* __restrict__ Wc2, const float* __restrict__ relb,
    ushort* __restrict__ gq_bf, ushort* __restrict__ t_bf, ushort* __restrict__ fc_bf,
    float* __restrict__ attn_o, float* __restrict__ conf_o)
{
    __shared__ ushort xt[NV][TP*128];   // swizzled [pix][c] bf16; xt[0] reused for fused
    __shared__ float  scat[NV][4][TP];
    __shared__ float  lpart[NV][TP];
    __shared__ float  cfw[NV][TP];

    const int t = threadIdx.x, lane = t & 63, w = t >> 6;
    // bijective XCD swizzle: 2048 blocks = 8 XCDs x 256 contiguous tiles.
    const int vb = ((blockIdx.x & 7) << 8) | (blockIdx.x >> 3);
    const int b = vb >> 9;
    const int pix0 = (vb & 511) * TP;

    // ---- Phase A: stage 6 views -> LDS bf16 swizzled; ALL loads in flight ----
    const int pixg = (t & 3) * 8;
    const int c0   = (t >> 2) * 2;
    const float* sb = bev + (((size_t)b*NV*CH + c0)*HWP + pix0 + pixg);
    const size_t vstep = (size_t)CH*HWP;
    float gacc[16];
#pragma unroll
    for (int i = 0; i < 16; ++i) gacc[i] = 0.f;
    float4 L[NV][4];                     // 24 loads issued back-to-back (static idx)
#pragma unroll
    for (int j = 0; j < NV; ++j) {
        const float* s1 = sb + (size_t)j*vstep;
        L[j][0] = *(const float4*)(s1);
        L[j][1] = *(const float4*)(s1 + 4);
        L[j][2] = *(const float4*)(s1 + HWP);
        L[j][3] = *(const float4*)(s1 + HWP + 4);
    }
#pragma unroll
    for (int n = 0; n < NV; ++n) {
        float4 a0 = L[n][0], a1 = L[n][1], b0 = L[n][2], b1 = L[n][3];
        float r0[8] = {a0.x,a0.y,a0.z,a0.w, a1.x,a1.y,a1.z,a1.w};
        float r1[8] = {b0.x,b0.y,b0.z,b0.w, b1.x,b1.y,b1.z,b1.w};
#pragma unroll
        for (int p = 0; p < 8; ++p) {
            int pix = pixg + p;
            unsigned pk = cvt_pk_bf16(r0[p], r1[p]);
            *(unsigned*)(&xt[n][(pix*128 + c0) ^ SWZ(pix)]) = pk;
            gacc[p]   += r0[p];
            gacc[8+p] += r1[p];
        }
    }
    {
        U8 g0, g1;
#pragma unroll
        for (int p = 0; p < 4; ++p) {
            g0.u[p] = cvt_pk_bf16(gacc[2*p]   * (1.0f/6.0f), gacc[2*p+1] * (1.0f/6.0f));
            g1.u[p] = cvt_pk_bf16(gacc[8+2*p] * (1.0f/6.0f), gacc[9+2*p] * (1.0f/6.0f));
        }
        ushort* gd = gq_bf + ((size_t)(b*CH + c0)*HWP + pix0 + pixg);
        *(bf16x8*)(gd)       = g0.v;
        *(bf16x8*)(gd + HWP) = g1.v;
    }
    __syncthreads();

    const int cl0 = (lane & 15);
    const int rg  = (lane >> 4) << 2;
    const float bqv0 = bq[w*32 + cl0],      bqv1 = bq[w*32 + 16 + cl0];
    const float bkv0 = bk[w*32 + cl0],      bkv1 = bk[w*32 + 16 + cl0];
    const float bvv0 = bv[w*32 + cl0],      bvv1 = bv[w*32 + 16 + cl0];
    const float bov0 = bo1[w*32 + cl0],     bov1 = bo1[w*32 + 16 + cl0];
    const float bc10 = bc1[cl0],            bc11 = bc1[16 + cl0];
    const float wc20 = Wc2[cl0],            wc21 = Wc2[16 + cl0];

    // ---- Pass 1: Q accumulated across views via MFMA; conf for assigned views ----
    f32x4 qf[2][2];
#pragma unroll
    for (int mf = 0; mf < 2; ++mf)
#pragma unroll
        for (int nfl = 0; nfl < 2; ++nfl) qf[mf][nfl] = (f32x4){0.f,0.f,0.f,0.f};
    bf16x8 Bq[2][4];
#pragma unroll
    for (int nfl = 0; nfl < 2; ++nfl)
#pragma unroll
        for (int ks = 0; ks < 4; ++ks) Bq[nfl][ks] = ldB(wqp, lane, ks, 2*w + nfl, 8);
#pragma unroll 2
    for (int n = 0; n < NV; ++n) {
        bf16x8 xA[2][4];
#pragma unroll
        for (int mf = 0; mf < 2; ++mf)
#pragma unroll
            for (int ks = 0; ks < 4; ++ks) xA[mf][ks] = ldsA(xt[n], lane, mf, ks);
#pragma unroll
        for (int nfl = 0; nfl < 2; ++nfl) {
#pragma unroll
            for (int ks = 0; ks < 4; ++ks) {
#pragma unroll
                for (int mf = 0; mf < 2; ++mf)
                    qf[mf][nfl] = __builtin_amdgcn_mfma_f32_16x16x32_bf16(xA[mf][ks], Bq[nfl][ks], qf[mf][nfl], 0, 0, 0);
            }
        }
        if (n == w || n == w + 4) {
            f32x4 cf[2][2];
#pragma unroll
            for (int mf = 0; mf < 2; ++mf)
#pragma unroll
                for (int nfc = 0; nfc < 2; ++nfc) cf[mf][nfc] = (f32x4){0.f,0.f,0.f,0.f};
#pragma unroll
            for (int nfc = 0; nfc < 2; ++nfc) {
#pragma unroll
                for (int ks = 0; ks < 4; ++ks) {
                    bf16x8 bb = ldB(wc1p, lane, ks, nfc, 2);
#pragma unroll
                    for (int mf = 0; mf < 2; ++mf)
                        cf[mf][nfc] = __builtin_amdgcn_mfma_f32_16x16x32_bf16(xA[mf][ks], bb, cf[mf][nfc], 0, 0, 0);
                }
            }
#pragma unroll
            for (int mf = 0; mf < 2; ++mf) {
#pragma unroll
                for (int r = 0; r < 4; ++r) {
                    float pl = fmaxf(cf[mf][0][r] + bc10, 0.f)*wc20
                             + fmaxf(cf[mf][1][r] + bc11, 0.f)*wc21;
                    pl += __shfl_xor(pl, 1, 64);
                    pl += __shfl_xor(pl, 2, 64);
                    pl += __shfl_xor(pl, 4, 64);
                    pl += __shfl_xor(pl, 8, 64);
                    if (cl0 == 0) lpart[n][mf*16 + rg + r] = pl;
                }
            }
        }
    }
#pragma unroll
    for (int mf = 0; mf < 2; ++mf)
#pragma unroll
        for (int r = 0; r < 4; ++r) {
            qf[mf][0][r] = qf[mf][0][r]*(1.0f/6.0f) + bqv0;
            qf[mf][1][r] = qf[mf][1][r]*(1.0f/6.0f) + bqv1;
        }

    // ---- Pass 2: K per view -> scores ----
    bf16x8 Bk[2][4];
#pragma unroll
    for (int nfl = 0; nfl < 2; ++nfl)
#pragma unroll
        for (int ks = 0; ks < 4; ++ks) Bk[nfl][ks] = ldB(wkp, lane, ks, 2*w + nfl, 8);
#pragma unroll 2
    for (int n = 0; n < NV; ++n) {
        bf16x8 xA[2][4];
#pragma unroll
        for (int mf = 0; mf < 2; ++mf)
#pragma unroll
            for (int ks = 0; ks < 4; ++ks) xA[mf][ks] = ldsA(xt[n], lane, mf, ks);
        f32x4 kf[2][2];
#pragma unroll
        for (int mf = 0; mf < 2; ++mf)
#pragma unroll
            for (int nfl = 0; nfl < 2; ++nfl) kf[mf][nfl] = (f32x4){0.f,0.f,0.f,0.f};
#pragma unroll
        for (int nfl = 0; nfl < 2; ++nfl) {
#pragma unroll
            for (int ks = 0; ks < 4; ++ks) {
#pragma unroll
                for (int mf = 0; mf < 2; ++mf)
                    kf[mf][nfl] = __builtin_amdgcn_mfma_f32_16x16x32_bf16(xA[mf][ks], Bk[nfl][ks], kf[mf][nfl], 0, 0, 0);
            }
        }
#pragma unroll
        for (int mf = 0; mf < 2; ++mf) {
#pragma unroll
            for (int r = 0; r < 4; ++r) {
                float s = qf[mf][0][r]*(kf[mf][0][r] + bkv0) + qf[mf][1][r]*(kf[mf][1][r] + bkv1);
                s += __shfl_xor(s, 1, 64);
                s += __shfl_xor(s, 2, 64);
                s += __shfl_xor(s, 4, 64);
                s += __shfl_xor(s, 8, 64);
                if (cl0 == 0) scat[n][w][mf*16 + rg + r] = s * 0.17677669529663687f;
            }
        }
    }
    __syncthreads();

    // ---- Phase D: attn softmax (t<128) || conf softmax (128<=t<160) ----
    if (t < 128) {
        int h = t >> 5, pix = t & 31;
        float s0 = scat[0][h][pix], s1 = scat[1][h][pix], s2 = scat[2][h][pix],
              s3 = scat[3][h][pix], s4 = scat[4][h][pix], s5 = scat[5][h][pix];
        float mx = fmaxf(fmaxf(fmaxf(s0,s1),fmaxf(s2,s3)),fmaxf(s4,s5));
        float e0=__expf(s0-mx), e1=__expf(s1-mx), e2=__expf(s2-mx),
              e3=__expf(s3-mx), e4=__expf(s4-mx), e5=__expf(s5-mx);
        float inv = 1.0f/(e0+e1+e2+e3+e4+e5);
        scat[0][h][pix]=e0*inv; scat[1][h][pix]=e1*inv; scat[2][h][pix]=e2*inv;
        scat[3][h][pix]=e3*inv; scat[4][h][pix]=e4*inv; scat[5][h][pix]=e5*inv;
    } else if (t < 160) {
        int pix = t - 128;
        float bc2v = bc2[0];
        float lg[NV];
#pragma unroll
        for (int n = 0; n < NV; ++n)
            lg[n] = lpart[n][pix] + bc2v + relb[b*NV + n];
        float mx = fmaxf(fmaxf(fmaxf(lg[0],lg[1]),fmaxf(lg[2],lg[3])),fmaxf(lg[4],lg[5]));
        float e[NV], sum = 0.f;
#pragma unroll
        for (int n = 0; n < NV; ++n) { e[n] = __expf(lg[n]-mx); sum += e[n]; }
        float inv = 1.0f/sum;
#pragma unroll
        for (int n = 0; n < NV; ++n) {
            float wv = e[n]*inv;
            cfw[n][pix] = wv;
            conf_o[(b*NV + n)*HWP + pix0 + pix] = wv;
        }
    }
    __syncthreads();

    // ---- Pass 3: V per view via MFMA, attn-scale C-regs ----
    f32x4 ff[2][2];
#pragma unroll
    for (int mf = 0; mf < 2; ++mf)
#pragma unroll
        for (int nfl = 0; nfl < 2; ++nfl) ff[mf][nfl] = (f32x4){0.f,0.f,0.f,0.f};
    bf16x8 Bv[2][4];
#pragma unroll
    for (int nfl = 0; nfl < 2; ++nfl)
#pragma unroll
        for (int ks = 0; ks < 4; ++ks) Bv[nfl][ks] = ldB(wvp, lane, ks, 2*w + nfl, 8);
#pragma unroll 2
    for (int n = 0; n < NV; ++n) {
        bf16x8 xA[2][4];
#pragma unroll
        for (int mf = 0; mf < 2; ++mf)
#pragma unroll
            for (int ks = 0; ks < 4; ++ks) xA[mf][ks] = ldsA(xt[n], lane, mf, ks);
        f32x4 vv[2][2];
#pragma unroll
        for (int mf = 0; mf < 2; ++mf)
#pragma unroll
            for (int nfl = 0; nfl < 2; ++nfl) vv[mf][nfl] = (f32x4){0.f,0.f,0.f,0.f};
#pragma unroll
        for (int nfl = 0; nfl < 2; ++nfl) {
#pragma unroll
            for (int ks = 0; ks < 4; ++ks) {
#pragma unroll
                for (int mf = 0; mf < 2; ++mf)
                    vv[mf][nfl] = __builtin_amdgcn_mfma_f32_16x16x32_bf16(xA[mf][ks], Bv[nfl][ks], vv[mf][nfl], 0, 0, 0);
            }
        }
#pragma unroll
        for (int mf = 0; mf < 2; ++mf) {
#pragma unroll
            for (int r = 0; r < 4; ++r) {
                float a = scat[n][w][mf*16 + rg + r];
                ff[mf][0][r] += a * vv[mf][0][r];
                ff[mf][1][r] += a * vv[mf][1][r];
            }
        }
    }
#pragma unroll
    for (int mf = 0; mf < 2; ++mf)
#pragma unroll
        for (int r = 0; r < 4; ++r) { ff[mf][0][r] += bvv0; ff[mf][1][r] += bvv1; }

    // ---- fc = sum_n cfw[n]*x_n -> fc_bf NCHW bf16 ----
    {
        float fcv[16];
#pragma unroll
        for (int i = 0; i < 16; ++i) fcv[i] = 0.f;
#pragma unroll
        for (int n = 0; n < NV; ++n) {
#pragma unroll
            for (int p = 0; p < 8; ++p) {
                int pix = pixg + p;
                float cwv = cfw[n][pix];
                unsigned pk = *(const unsigned*)(&xt[n][(pix*128 + c0) ^ SWZ(pix)]);
                fcv[p]   += cwv * bf2f((ushort)(pk & 0xffffu));
                fcv[8+p] += cwv * bf2f((ushort)(pk >> 16));
            }
        }
        U8 f0, f1;
#pragma unroll
        for (int p = 0; p < 4; ++p) {
            f0.u[p] = cvt_pk_bf16(fcv[2*p],   fcv[2*p+1]);
            f1.u[p] = cvt_pk_bf16(fcv[8+2*p], fcv[9+2*p]);
        }
        ushort* fd = fc_bf + ((size_t)(b*CH + c0)*HWP + pix0 + pixg);
        *(bf16x8*)(fd)       = f0.v;
        *(bf16x8*)(fd + HWP) = f1.v;
    }
    if (t < 192) {
        int n = t >> 5, pix = t & 31;
        float am = 0.25f*(scat[n][0][pix]+scat[n][1][pix]+scat[n][2][pix]+scat[n][3][pix]);
        attn_o[(b*NV + n)*HWP + pix0 + pix] = am;
    }
    __syncthreads();

    // ---- fused frags -> xt[0] (swizzled) ----
    {
        ushort* xt0 = &xt[0][0];
#pragma unroll
        for (int mf = 0; mf < 2; ++mf)
#pragma unroll
            for (int nfl = 0; nfl < 2; ++nfl)
#pragma unroll
                for (int r = 0; r < 4; ++r) {
                    int pix = mf*16 + rg + r;
                    int c   = w*32 + nfl*16 + cl0;
                    xt0[(pix*128 + c) ^ SWZ(pix)] = f2bf(ff[mf][nfl][r]);
                }
    }
    __syncthreads();

    // ---- Phase F: t = relu(Wo1 @ fused + bo1) -> t_bf NHWC bf16 ----
    {
        bf16x8 aA[2][4];
#pragma unroll
        for (int mf = 0; mf < 2; ++mf)
#pragma unroll
            for (int ks = 0; ks < 4; ++ks) aA[mf][ks] = ldsA(&xt[0][0], lane, mf, ks);
        f32x4 tf[2][2];
#pragma unroll
        for (int mf = 0; mf < 2; ++mf)
#pragma unroll
            for (int nfl = 0; nfl < 2; ++nfl) tf[mf][nfl] = (f32x4){0.f,0.f,0.f,0.f};
#pragma unroll
        for (int nfl = 0; nfl < 2; ++nfl) {
            int nf = 2*w + nfl;
#pragma unroll
            for (int ks = 0; ks < 4; ++ks) {
                bf16x8 bb = ldB(wo1p, lane, ks, nf, 8);
#pragma unroll
                for (int mf = 0; mf < 2; ++mf)
                    tf[mf][nfl] = __builtin_amdgcn_mfma_f32_16x16x32_bf16(aA[mf][ks], bb, tf[mf][nfl], 0, 0, 0);
            }
        }
#pragma unroll
        for (int mf = 0; mf < 2; ++mf)
#pragma unroll
            for (int nfl = 0; nfl < 2; ++nfl)
#pragma unroll
                for (int r = 0; r < 4; ++r) {
                    int pix = mf*16 + rg + r;
                    int c   = w*32 + nfl*16 + cl0;
                    float bo_ = nfl ? bov1 : bov0;
                    t_bf[(size_t)(b*HWP + pix0 + pix)*128 + c] = f2bf(fmaxf(tf[mf][nfl][r] + bo_, 0.f));
                }
    }
}

// ---------------- conv3x3 as implicit-GEMM MFMA + gate blend (chunked pipeline) ----------------
__global__ __launch_bounds__(256, 1) void fusion_conv3(
    const ushort* __restrict__ t_bf, const ushort* __restrict__ gq_bf,
    const ushort* __restrict__ fc_bf, const ushort* __restrict__ wo2p,
    const float* __restrict__ bo2, const float* __restrict__ gate,
    float* __restrict__ out)
{
    __shared__ ushort halo[2][18*18*64];

    const int t = threadIdx.x, lane = t & 63, w = t >> 6;
    const int b = blockIdx.x >> 6;
    const int tile = blockIdx.x & 63;
    const int h0 = (tile >> 3) * 16;
    const int w0 = (tile & 7) * 16;

    const int c8   = (t & 7) * 8;
    const int cell0 = t >> 3;

    for (int i = cell0; i < 324; i += 32) {
        int r = i / 18, cc = i - r*18;
        int hs = h0 - 1 + r, wsr = w0 - 1 + cc;
        bf16x8 v = (bf16x8){0,0,0,0,0,0,0,0};
        if ((unsigned)hs < (unsigned)HGT && (unsigned)wsr < (unsigned)WID)
            v = *(const bf16x8*)(t_bf + ((size_t)(b*HWP + hs*WID + wsr)*128 + c8));
        *(bf16x8*)(&halo[0][(i*64 + c8) ^ ((cc & 7) << 3)]) = v;
    }
    bf16x8 stg[11];
#pragma unroll
    for (int j = 0; j < 11; ++j) {
        int i = cell0 + 32*j;
        if (i < 324) {
            int r = i / 18, cc = i - r*18;
            int hs = h0 - 1 + r, wsr = w0 - 1 + cc;
            bf16x8 v = (bf16x8){0,0,0,0,0,0,0,0};
            if ((unsigned)hs < (unsigned)HGT && (unsigned)wsr < (unsigned)WID)
                v = *(const bf16x8*)(t_bf + ((size_t)(b*HWP + hs*WID + wsr)*128 + 64 + c8));
            stg[j] = v;
        }
    }
    __syncthreads();

    f32x4 acc[4][8];
#pragma unroll
    for (int mi = 0; mi < 4; ++mi)
#pragma unroll
        for (int nf = 0; nf < 8; ++nf) acc[mi][nf] = (f32x4){0.f,0.f,0.f,0.f};

    const int mcol = lane & 15;
    const int koff = (lane >> 4) << 3;

#pragma unroll 1
    for (int k = 0; k < 2; ++k) {
#pragma unroll 1
        for (int tap = 0; tap < 9; ++tap) {
            const int dy = tap / 3, dx = tap - dy*3;
            const int col = mcol + dx;
            const int swz = (col & 7) << 3;
#pragma unroll
            for (int ks2 = 0; ks2 < 2; ++ks2) {
                bf16x8 Bf[8];
#pragma unroll
                for (int nf = 0; nf < 8; ++nf)
                    Bf[nf] = *(const bf16x8*)(wo2p + (((size_t)((tap*4 + k*2 + ks2)*8 + nf))*64 + lane)*8);
#pragma unroll
                for (int mi = 0; mi < 4; ++mi) {
                    int mf = w*4 + mi;
                    int idx = (((mf + dy)*18 + col)*64 + ks2*32 + koff) ^ swz;
                    bf16x8 Af = *(const bf16x8*)(&halo[k][idx]);
#pragma unroll
                    for (int nf = 0; nf < 8; ++nf)
                        acc[mi][nf] = __builtin_amdgcn_mfma_f32_16x16x32_bf16(Af, Bf[nf], acc[mi][nf], 0, 0, 0);
                }
            }
        }
        if (k == 0) {
#pragma unroll
            for (int j = 0; j < 11; ++j) {
                int i = cell0 + 32*j;
                if (i < 324) {
                    int cc = i % 18;
                    *(bf16x8*)(&halo[1][(i*64 + c8) ^ ((cc & 7) << 3)]) = stg[j];
                }
            }
            __syncthreads();
        }
    }
    __syncthreads();

    float* fbuf = (float*)halo;
    const int cl0 = lane & 15;
    const int rg  = (lane >> 4) << 2;
    const int c_l = t & 63;
    const int rgw = (t >> 6) * 4;
#pragma unroll 1
    for (int nfg = 0; nfg < 2; ++nfg) {
#pragma unroll
        for (int mi = 0; mi < 4; ++mi)
#pragma unroll
            for (int nl = 0; nl < 4; ++nl) {
                int nf = nfg*4 + nl;
                int pix = (w*4 + mi)*16 + rg;
                *(f32x4*)(fbuf + (nl*16 + cl0)*260 + pix) = acc[mi][nf];
            }
        __syncthreads();
        {
            const int c  = nfg*64 + c_l;
            const float gt  = gate[b*CH + c];
            const float gti = 1.0f - gt;
            const float b2v = bo2[c];
#pragma unroll
            for (int rr = 0; rr < 4; ++rr) {
                int row = rgw + rr;
                const int gbase = (b*CH + c)*HWP + (h0 + row)*WID + w0;
                float vv[16];
#pragma unroll
                for (int q = 0; q < 2; ++q) {
                    f32x4 cv0 = *(const f32x4*)(fbuf + c_l*260 + row*16 + q*8);
                    f32x4 cv1 = *(const f32x4*)(fbuf + c_l*260 + row*16 + q*8 + 4);
                    bf16x8 gq8 = *(const bf16x8*)(gq_bf + gbase + q*8);
                    bf16x8 fc8 = *(const bf16x8*)(fc_bf + gbase + q*8);
#pragma unroll
                    for (int jj = 0; jj < 4; ++jj) {
                        vv[q*8+jj]   = gt*(cv0[jj] + b2v + bf2f((ushort)gq8[jj]))   + gti*bf2f((ushort)fc8[jj]);
                        vv[q*8+4+jj] = gt*(cv1[jj] + b2v + bf2f((ushort)gq8[4+jj])) + gti*bf2f((ushort)fc8[4+jj]);
                    }
                }
                float* od = out + gbase;
                *(float4*)(od)      = (float4){vv[0],vv[1],vv[2],vv[3]};
                *(float4*)(od + 4)  = (float4){vv[4],vv[5],vv[6],vv[7]};
                *(float4*)(od + 8)  = (float4){vv[8],vv[9],vv[10],vv[11]};
                *(float4*)(od + 12) = (float4){vv[12],vv[13],vv[14],vv[15]};
            }
        }
        __syncthreads();
    }
}

extern "C" void kernel_launch(void* const* d_in, const int* in_sizes, int n_in,
                              void* d_out, int out_size, void* d_ws, size_t ws_size,
                              hipStream_t stream)
{
    const float* bev = (const float*)d_in[0];
    const float* snr = (const float*)d_in[1];
    const float* vr  = (const float*)d_in[2];
    const float* Wq  = (const float*)d_in[3];
    const float* bq  = (const float*)d_in[4];
    const float* Wk  = (const float*)d_in[5];
    const float* bk  = (const float*)d_in[6];
    const float* Wv  = (const float*)d_in[7];
    const float* bv  = (const float*)d_in[8];
    const float* Wo1 = (const float*)d_in[9];
    const float* bo1 = (const float*)d_in[10];
    const float* Wo2 = (const float*)d_in[11];
    const float* bo2 = (const float*)d_in[12];
    const float* Wc1 = (const float*)d_in[13];
    const float* bc1 = (const float*)d_in[14];
    const float* Wc2 = (const float*)d_in[15];
    const float* bc2 = (const float*)d_in[16];
    const float* Wg  = (const float*)d_in[17];
    const float* bg  = (const float*)d_in[18];
    const float* Wr1 = (const float*)d_in[19];
    const float* br1 = (const float*)d_in[20];
    const float* Wr2 = (const float*)d_in[21];
    const float* br2 = (const float*)d_in[22];

    char* wsb = (char*)d_ws;
    ushort* t_bf  = (ushort*)(wsb);                       // 16 MB
    ushort* gq_bf = (ushort*)(wsb + 16777216);            // 16 MB
    ushort* fc_bf = (ushort*)(wsb + 33554432);            // 16 MB
    ushort* wqp   = (ushort*)(wsb + 50331648);
    ushort* wkp   = wqp + 16384;
    ushort* wvp   = wkp + 16384;
    ushort* wo1p  = wvp + 16384;
    ushort* wc1p  = wo1p + 16384;
    ushort* wo2p  = wc1p + 4096;                          // 147,456 ushorts
    float*  gate  = (float*)(wsb + 50331648 + 434176);
    float*  relb  = gate + 512;

    float* outp   = (float*)d_out;
    float* attn_o = outp + 8388608;
    float* conf_o = outp + 8781824;

    fusion_setup<<<2, 256, 0, stream>>>(snr, vr, Wg, bg, Wr1, br1, Wr2, br2,
                                        relb, gate);
    pack_weights<<<106, 256, 0, stream>>>(Wq, Wk, Wv, Wo1, Wc1, Wo2,
                                          wqp, wkp, wvp, wo1p, wc1p, wo2p);
    fusion_attn<<<2048, 256, 0, stream>>>(bev, wqp, wkp, wvp, wo1p, wc1p,
                                          bq, bk, bv, bo1, bc1, bc2, Wc2, relb,
                                          gq_bf, t_bf, fc_bf, attn_o, conf_o);
    fusion_conv3<<<256, 256, 0, stream>>>(t_bf, gq_bf, fc_bf, wo2p, bo2, gate, outp);
}